// Round 3
// baseline (443.986 us; speedup 1.0000x reference)
//
#include <hip/hip_runtime.h>

#define NC 8192
#define NT 4096
#define NLAGS 103        // lag index 0..102 ; actual lag = idx - 51
#define WS_STRIDE 104    // row stride in scratch
#define LPW 28           // lags per wave; wave w covers L in [28w-1, 28w+27)
#define D1OFF 52         // left zero pad (makes all window reads 16B-aligned)
#define D1SZ 4272        // 52 zeros + 4096 data + 124 zeros
#define SMEMF (D1SZ + NT)   // 8368 floats = 33.5 KB -> 4 blocks/CU
#define XBASE (NC*NLAGS)

// ---------------- Kernel 1: per-channel cross-correlation ----------------
// One block (256 threads = 4 waves) per channel.
// R[L] = sum_k data1[k+L-51]*data2[k]. Buffer index of data1[i] is i+52, so
// the window read base = k0 + 4*lane + (l0+1) with l0 = 28w-1 == 3 mod 4
// => base == 0 mod 4: every LDS access is a lane-contiguous, 16B-aligned
// ds_read_b128 (lane stride 4 dwords = the conflict-free b128 pattern).
__global__ __launch_bounds__(256, 4)
void xcorr_kernel(const float* __restrict__ g1, const float* __restrict__ g2,
                  float* __restrict__ ws) {
    __shared__ __align__(16) float smem[SMEMF];
    float* d1s = smem;                 // [0,52) zeros | data1 | [4148,4272) zeros
    float* d2s = smem + D1SZ;
    const int c   = blockIdx.x;
    const int tid = threadIdx.x;
    const float4* r14 = (const float4*)(g1 + (size_t)c * NT);
    const float4* r24 = (const float4*)(g2 + (size_t)c * NT);

    #pragma unroll
    for (int i = 0; i < 4; ++i) {      // contiguous b128 stores, conflict-free
        ((float4*)(d1s + D1OFF))[tid + 256*i] = r14[tid + 256*i];
        ((float4*)d2s)[tid + 256*i]           = r24[tid + 256*i];
    }
    if (tid < D1OFF) d1s[tid] = 0.f;                   // left pad
    if (tid < 124)   d1s[D1OFF + NT + tid] = 0.f;      // right pad
    __syncthreads();

    const int wv   = tid >> 6;
    const int lane = tid & 63;
    const int l0   = LPW*wv - 1;       // {-1, 27, 55, 83}
    const int wb0  = 4*lane + LPW*wv;  // window base (== l0+1 + 4*lane), %4==0

    float acc[LPW];
    #pragma unroll
    for (int l = 0; l < LPW; ++l) acc[l] = 0.f;

    #pragma unroll 1
    for (int p = 0; p < 16; ++p) {     // 16 panels of 256 k
        const int k0 = p << 8;
        float w[32];
        #pragma unroll
        for (int t = 0; t < 8; ++t) {  // 8 contiguous b128: window w[0..31]
            float4 v = *(const float4*)&d1s[k0 + wb0 + 4*t];
            w[4*t]=v.x; w[4*t+1]=v.y; w[4*t+2]=v.z; w[4*t+3]=v.w;
        }
        float4 bv = *(const float4*)&d2s[k0 + 4*lane];
        const float b[4] = {bv.x, bv.y, bv.z, bv.w};
        #pragma unroll
        for (int j = 0; j < 4; ++j)    // acc[l] += d1[k+L-51]*d2[k]
            #pragma unroll
            for (int l = 0; l < LPW; ++l)
                acc[l] = fmaf(w[j + l], b[j], acc[l]);
    }

    // ---- reduce 64 lanes' partials (reuse smem; stride 29 = odd, no conflicts)
    __syncthreads();
    float* red = smem + wv * (64*29);
    #pragma unroll
    for (int l = 0; l < LPW; ++l) red[lane*29 + l] = acc[l];
    // same-wave DS ops complete in order; no barrier needed
    float sum = 0.f;
    const int lcol = lane & 31;
    const int rb   = lane & 32;
    #pragma unroll
    for (int r = 0; r < 32; ++r) sum += red[(rb + r)*29 + lcol];
    sum += __shfl_down(sum, 32);
    const int L = l0 + lcol;
    if (lane < LPW && L >= 0 && L < NLAGS)
        ws[(size_t)c * WS_STRIDE + L] = sum;
}

// -------- Kernel 2: moving average across channels + pick max|R| --------
#define TS 112   // tile stride (rows alias 2-way = free)
__global__ __launch_bounds__(256, 4)
void ma_pick_kernel(const float* __restrict__ ws, float* __restrict__ out) {
    __shared__ float tile[52*TS];
    __shared__ float matile[32*TS];
    const int tid = threadIdx.x;
    const int c0  = blockIdx.x * 32;

    for (int i = tid; i < 52*TS; i += 256) {
        int r   = i / TS;
        int col = i - r*TS;
        int g   = c0 - 10 + r;
        float v = 0.f;
        if (g >= 0 && g < NC && col < NLAGS) v = ws[(size_t)g*WS_STRIDE + col];
        tile[i] = v;
    }
    __syncthreads();

    {   // rolling 20-channel window sum; thread = one lag, 16 channels
        const int l = tid & 127;
        const int h = tid >> 7;
        if (l < NLAGS) {
            const int cc0 = h * 16;
            float s = 0.f;
            #pragma unroll
            for (int r = 0; r < 20; ++r) s += tile[(cc0 + r)*TS + l];
            #pragma unroll 1
            for (int cc = cc0; cc < cc0 + 16; ++cc) {
                float ma = s / 20.0f;
                matile[cc*TS + l] = ma;
                out[(size_t)(c0 + cc)*NLAGS + l] = ma;   // coalesced across l
                s += tile[(cc + 20)*TS + l] - tile[cc*TS + l];
            }
        }
    }
    __syncthreads();

    // per-channel argmax|R| (first-index tie-break), max, min
    const int wv = tid >> 6, lane = tid & 63;
    #pragma unroll 1
    for (int s8 = 0; s8 < 8; ++s8) {
        const int cc = wv*8 + s8;
        float v1 = matile[cc*TS + lane];
        float a1 = fabsf(v1);
        int   i1 = lane;
        float vmx = v1, vmn = v1;
        if (lane < NLAGS - 64) {                 // second element: l = lane+64
            float v2 = matile[cc*TS + 64 + lane];
            float a2 = fabsf(v2);
            vmx = fmaxf(vmx, v2); vmn = fminf(vmn, v2);
            if (a2 > a1) { a1 = a2; i1 = 64 + lane; v1 = v2; }
        }
        #pragma unroll
        for (int d = 32; d >= 1; d >>= 1) {
            float oa  = __shfl_xor(a1, d);
            int   oi  = __shfl_xor(i1, d);
            float ov  = __shfl_xor(v1, d);
            float omx = __shfl_xor(vmx, d);
            float omn = __shfl_xor(vmn, d);
            vmx = fmaxf(vmx, omx);
            vmn = fminf(vmn, omn);
            if (oa > a1 || (oa == a1 && oi < i1)) { a1 = oa; i1 = oi; v1 = ov; }
        }
        if (lane == 0) {
            const int ch = c0 + cc;
            out[XBASE + ch]        = v1;                         // vmain
            out[XBASE + NC + ch]   = (v1 >= 0.f) ? vmn : vmx;    // vside
            out[XBASE + 2*NC + ch] = (float)(i1 - 51) * 0.01f;   // tmax
        }
    }
}

extern "C" void kernel_launch(void* const* d_in, const int* in_sizes, int n_in,
                              void* d_out, int out_size, void* d_ws, size_t ws_size,
                              hipStream_t stream) {
    const float* g1 = (const float*)d_in[0];
    const float* g2 = (const float*)d_in[1];
    float* out = (float*)d_out;
    float* ws  = (float*)d_ws;   // 8192*104*4 = 3.4 MB scratch

    hipLaunchKernelGGL(xcorr_kernel, dim3(NC), dim3(256), 0, stream, g1, g2, ws);
    hipLaunchKernelGGL(ma_pick_kernel, dim3(NC/32), dim3(256), 0, stream, ws, out);
}

// Round 5
// 346.751 us; speedup vs baseline: 1.2804x; 1.2804x over previous
//
#include <hip/hip_runtime.h>

#define NC 8192
#define NT 4096
#define NLAGS 103        // lag index 0..102 ; actual lag = idx - 51
#define WS_STRIDE 104
#define LPW 28           // lags per wave; wave w: L in [28w-1, 28w+27)
#define D1SZ 4208        // 52 zeros | 4096 data | 60 zeros
#define XBASE (NC*NLAGS)

template <int CTRL, int RMASK>
__device__ __forceinline__ float dpp_add(float v) {
    return v + __int_as_float(__builtin_amdgcn_update_dpp(
        0, __float_as_int(v), CTRL, RMASK, 0xf, false));
}

// ---------------- Kernel 1: per-channel cross-correlation ----------------
// One block (4 waves) per channel. Waves split lags (28 each); lanes split k
// (64 consecutive each). d1 window: 32-reg ring fed by 1 ds_read_b128 per
// 4 k-steps (23 b128/thread total). d2: per-lane-private -> global loads
// (VMEM pipe), never LDS. Reduction: DPP row_shr/row_bcast (VALU only).
// LDS/block ~110 b128; VALU/block ~2100 instr/thread -> VALU-bound.
__global__ __launch_bounds__(256, 4)
void xcorr_kernel(const float* __restrict__ g1, const float* __restrict__ g2,
                  float* __restrict__ ws) {
    __shared__ __align__(16) float d1s[D1SZ];   // d1s[i] = d1[i-52]
    const int c   = blockIdx.x;
    const int tid = threadIdx.x;
    const float4* r14 = (const float4*)(g1 + (size_t)c * NT);
    #pragma unroll
    for (int i = 0; i < 4; ++i)
        ((float4*)(d1s + 52))[tid + 256*i] = r14[tid + 256*i];
    if (tid < 52) d1s[tid] = 0.f;
    if (tid < 60) d1s[52 + NT + tid] = 0.f;
    __syncthreads();

    const int wv = tid >> 6, lane = tid & 63;
    const int l0 = LPW*wv - 1;                   // {-1,27,55,83}
    // read addr for (j,l) = 64*lane + j + l0 + l + 1 ; base % 4 == 0
    const float* wp = d1s + 64*lane + LPW*wv;
    const float4* gb = (const float4*)(g2 + (size_t)c * NT) + 16*lane;

    float acc[LPW];
    #pragma unroll
    for (int l = 0; l < LPW; ++l) acc[l] = 0.f;

    float ring[32];                              // holds W(x), x in [4c, 4c+32)
    #pragma unroll
    for (int t = 0; t < 8; ++t) {
        float4 v = *(const float4*)(wp + 4*t);
        ring[4*t]=v.x; ring[4*t+1]=v.y; ring[4*t+2]=v.z; ring[4*t+3]=v.w;
    }
    float4 b0 = gb[0], b1 = gb[1];               // 2-deep d2 prefetch

    #pragma unroll
    for (int half = 0; half < 2; ++half)
    {
        #pragma unroll
        for (int cc = 0; cc < 8; ++cc) {
            const int ch = half*8 + cc;          // chunk = 4 k-steps
            float4 bc = b0; b0 = b1;
            if (ch + 2 < 16) b1 = gb[ch + 2];
            const float bb[4] = {bc.x, bc.y, bc.z, bc.w};
            #pragma unroll
            for (int r = 0; r < 4; ++r)
                #pragma unroll
                for (int l = 0; l < LPW; ++l)
                    acc[l] = fmaf(ring[(4*ch + r + l) & 31], bb[r], acc[l]);
            if (ch < 15) {                       // refill: W(4ch+32..4ch+35)
                float4 v = *(const float4*)(wp + 4*ch + 32);
                ring[(4*ch)     & 31] = v.x;
                ring[(4*ch + 1) & 31] = v.y;
                ring[(4*ch + 2) & 31] = v.z;
                ring[(4*ch + 3) & 31] = v.w;
            }
        }
    }

    // ---- cross-lane sum via DPP (rocPRIM canonical; total lands in lane 63)
    #pragma unroll
    for (int l = 0; l < LPW; ++l) {
        float v = acc[l];
        v = dpp_add<0x111, 0xf>(v);   // row_shr:1
        v = dpp_add<0x112, 0xf>(v);   // row_shr:2
        v = dpp_add<0x114, 0xf>(v);   // row_shr:4
        v = dpp_add<0x118, 0xf>(v);   // row_shr:8
        v = dpp_add<0x142, 0xa>(v);   // row_bcast:15 -> rows 1,3
        v = dpp_add<0x143, 0xc>(v);   // row_bcast:31 -> rows 2,3
        acc[l] = v;
    }
    if (lane == 63) {
        #pragma unroll
        for (int l = 0; l < LPW; ++l) {
            const int L = l0 + l;
            if (L >= 0 && L < NLAGS)
                ws[(size_t)c * WS_STRIDE + L] = acc[l];
        }
    }
}

// -------- Kernel 2: moving average across channels + pick max|R| --------
#define TS 112
__global__ __launch_bounds__(256, 4)
void ma_pick_kernel(const float* __restrict__ ws, float* __restrict__ out) {
    __shared__ float tile[52*TS];
    __shared__ float matile[32*TS];
    const int tid = threadIdx.x;
    const int c0  = blockIdx.x * 32;

    for (int i = tid; i < 52*TS; i += 256) {
        int r   = i / TS;
        int col = i - r*TS;
        int g   = c0 - 10 + r;
        float v = 0.f;
        if (g >= 0 && g < NC && col < NLAGS) v = ws[(size_t)g*WS_STRIDE + col];
        tile[i] = v;
    }
    __syncthreads();

    {   // rolling 20-channel window sum; thread = one lag, 16 channels
        const int l = tid & 127;
        const int h = tid >> 7;
        if (l < NLAGS) {
            const int cc0 = h * 16;
            float s = 0.f;
            #pragma unroll
            for (int r = 0; r < 20; ++r) s += tile[(cc0 + r)*TS + l];
            #pragma unroll 1
            for (int cc = cc0; cc < cc0 + 16; ++cc) {
                float ma = s / 20.0f;
                matile[cc*TS + l] = ma;
                out[(size_t)(c0 + cc)*NLAGS + l] = ma;
                s += tile[(cc + 20)*TS + l] - tile[cc*TS + l];
            }
        }
    }
    __syncthreads();

    // per-channel argmax|R| (first-index tie-break), max, min
    const int wv = tid >> 6, lane = tid & 63;
    #pragma unroll 1
    for (int s8 = 0; s8 < 8; ++s8) {
        const int cc = wv*8 + s8;
        float v1 = matile[cc*TS + lane];
        float a1 = fabsf(v1);
        int   i1 = lane;
        float vmx = v1, vmn = v1;
        if (lane < NLAGS - 64) {
            float v2 = matile[cc*TS + 64 + lane];
            float a2 = fabsf(v2);
            vmx = fmaxf(vmx, v2); vmn = fminf(vmn, v2);
            if (a2 > a1) { a1 = a2; i1 = 64 + lane; v1 = v2; }
        }
        #pragma unroll
        for (int d = 32; d >= 1; d >>= 1) {
            float oa  = __shfl_xor(a1, d);
            int   oi  = __shfl_xor(i1, d);
            float ov  = __shfl_xor(v1, d);
            float omx = __shfl_xor(vmx, d);
            float omn = __shfl_xor(vmn, d);
            vmx = fmaxf(vmx, omx);
            vmn = fminf(vmn, omn);
            if (oa > a1 || (oa == a1 && oi < i1)) { a1 = oa; i1 = oi; v1 = ov; }
        }
        if (lane == 0) {
            const int chn = c0 + cc;
            out[XBASE + chn]        = v1;
            out[XBASE + NC + chn]   = (v1 >= 0.f) ? vmn : vmx;
            out[XBASE + 2*NC + chn] = (float)(i1 - 51) * 0.01f;
        }
    }
}

extern "C" void kernel_launch(void* const* d_in, const int* in_sizes, int n_in,
                              void* d_out, int out_size, void* d_ws, size_t ws_size,
                              hipStream_t stream) {
    const float* g1 = (const float*)d_in[0];
    const float* g2 = (const float*)d_in[1];
    float* out = (float*)d_out;
    float* ws  = (float*)d_ws;   // 8192*104*4 = 3.4 MB scratch

    hipLaunchKernelGGL(xcorr_kernel, dim3(NC), dim3(256), 0, stream, g1, g2, ws);
    hipLaunchKernelGGL(ma_pick_kernel, dim3(NC/32), dim3(256), 0, stream, ws, out);
}